// Round 18
// baseline (235.471 us; speedup 1.0000x reference)
//
#include <hip/hip_runtime.h>
#include <math.h>

#define DIN 3072
#define DF 640
#define MROWS 400
#define QROWS 240
#define NMAT 400
#define PN 416          // padded A dim (13*32, 26*16)
#define NRHS 16
#define CREG 50.0f
#define PVSTEPS 5
#define CSTEPS 25       // Chebyshev: 2*q^25 ~ 3.5e-3 rel (q~0.78)
#define KSPLIT 8        // feat split-K factor
#define GBLK 13         // solve blocks; each owns 32 ROWS of A in LDS
#define SCOLS 32        // rows per solve block
#define FPAD 72         // feat staging pad (2-way-free banks, r8-proven)
#define MTILES 28       // M = FX@K^T: 4 row-tiles x 7 col-tiles of 64
#define DPAD 424        // 416+8 shorts

typedef __attribute__((ext_vector_type(8))) short bf8v;   // 8 bf16 (4 VGPRs)
typedef __attribute__((ext_vector_type(4))) short s4v;    // 4 bf16 (8 B)
typedef __attribute__((ext_vector_type(4))) float f32x4;  // MFMA acc

__device__ __forceinline__ short bf16_rn(float x) {
  unsigned u = __float_as_uint(x);
  u += 0x7FFFu + ((u >> 16) & 1u);
  return (short)(u >> 16);
}
__device__ __forceinline__ void split_sh(float x, short& h, short& l) {
  h = bf16_rn(x);
  float hf = __uint_as_float(((unsigned)(unsigned short)h) << 16);
  l = bf16_rn(x - hf);
}

// ---- feat split-K=8, 128x128 tiles + per-tile finisher reduce -------------
// 8th block to finish a tile (mod-8 counter; init-value-agnostic) sums the 8
// partial slices (same s-order as the old feat_reduce -> bit-identical) and
// writes Kh/Kl/FX. Tile (0,0)'s finisher also zeroes ctrl + out.
__global__ __launch_bounds__(256) void gemm_feat_sk(const float* __restrict__ S,
                                                    const float* __restrict__ Qm,
                                                    const float* __restrict__ Wb,
                                                    float* __restrict__ Acc,
                                                    unsigned* __restrict__ tcnt,
                                                    short* __restrict__ Kh,
                                                    short* __restrict__ Kl,
                                                    float* __restrict__ FX,
                                                    float* __restrict__ zbuf,
                                                    float* __restrict__ out) {
  __shared__ short Ash[128][FPAD];   // 18.4KB each; total 72KB
  __shared__ short Asl[128][FPAD];
  __shared__ short Bsh[128][FPAD];   // [col][k]
  __shared__ short Bsl[128][FPAD];
  __shared__ unsigned sOld;
  int tid = threadIdx.x;
  int wave = tid >> 6, lane = tid & 63, l16 = lane & 15, quad = lane >> 4;
  int wr = wave >> 1, wc = wave & 1;
  int by = blockIdx.y, bx = blockIdx.x, bz = blockIdx.z;
  int colBase = bx * 128;
  int kbeg = bz * (DIN / KSPLIT), kend = kbeg + (DIN / KSPLIT);
  int kc4 = (tid & 15) * 4;
  float4 ar4[8], br4[8];
  auto load_regs = [&](int kk) {
#pragma unroll
    for (int p = 0; p < 8; ++p) {
      int ar_ = by * 128 + (tid >> 4) + 16 * p;
      const float* srp = (ar_ < MROWS) ? (S + (size_t)ar_ * DIN)
                                       : (Qm + (size_t)(ar_ - MROWS) * DIN);
      ar4[p] = *reinterpret_cast<const float4*>(srp + kk + kc4);
      int kr = (tid >> 4) + 16 * (p & 3);
      int cb = colBase + (p >> 2) * 64 + kc4;
      br4[p] = *reinterpret_cast<const float4*>(Wb + (size_t)(kk + kr) * DF + cb);
    }
  };
  auto split_write = [&]() {
#pragma unroll
    for (int p = 0; p < 8; ++p) {
      int row = (tid >> 4) + 16 * p;
      s4v hv, lv; short h, l;
      split_sh(ar4[p].x, h, l); hv[0] = h; lv[0] = l;
      split_sh(ar4[p].y, h, l); hv[1] = h; lv[1] = l;
      split_sh(ar4[p].z, h, l); hv[2] = h; lv[2] = l;
      split_sh(ar4[p].w, h, l); hv[3] = h; lv[3] = l;
      *reinterpret_cast<s4v*>(&Ash[row][kc4]) = hv;
      *reinterpret_cast<s4v*>(&Asl[row][kc4]) = lv;
      int kr = (tid >> 4) + 16 * (p & 3);
      int cb = (p >> 2) * 64 + kc4;          // local col
      split_sh(br4[p].x, h, l); Bsh[cb + 0][kr] = h; Bsl[cb + 0][kr] = l;
      split_sh(br4[p].y, h, l); Bsh[cb + 1][kr] = h; Bsl[cb + 1][kr] = l;
      split_sh(br4[p].z, h, l); Bsh[cb + 2][kr] = h; Bsl[cb + 2][kr] = l;
      split_sh(br4[p].w, h, l); Bsh[cb + 3][kr] = h; Bsl[cb + 3][kr] = l;
    }
  };
  f32x4 acc[4][4];
#pragma unroll
  for (int m = 0; m < 4; ++m)
#pragma unroll
    for (int n = 0; n < 4; ++n) acc[m][n] = {0, 0, 0, 0};
  load_regs(kbeg);
  split_write();
  __syncthreads();
  int k0 = kbeg;
  while (true) {
    int kn = k0 + 64;
    bool more = (kn < kend);
    if (more) load_regs(kn);            // prefetch overlaps MFMA below
#pragma unroll
    for (int kk = 0; kk < 64; kk += 32) {
      int ko = kk + quad * 8;
      bf8v ah[4], al[4], bh[4], bl[4];
#pragma unroll
      for (int m = 0; m < 4; ++m) {
        ah[m] = *reinterpret_cast<const bf8v*>(&Ash[wr * 64 + m * 16 + l16][ko]);
        al[m] = *reinterpret_cast<const bf8v*>(&Asl[wr * 64 + m * 16 + l16][ko]);
      }
#pragma unroll
      for (int n = 0; n < 4; ++n) {
        bh[n] = *reinterpret_cast<const bf8v*>(&Bsh[wc * 64 + n * 16 + l16][ko]);
        bl[n] = *reinterpret_cast<const bf8v*>(&Bsl[wc * 64 + n * 16 + l16][ko]);
      }
#pragma unroll
      for (int m = 0; m < 4; ++m)
#pragma unroll
        for (int n = 0; n < 4; ++n) {
          acc[m][n] = __builtin_amdgcn_mfma_f32_16x16x32_bf16(ah[m], bh[n], acc[m][n], 0, 0, 0);
          acc[m][n] = __builtin_amdgcn_mfma_f32_16x16x32_bf16(ah[m], bl[n], acc[m][n], 0, 0, 0);
          acc[m][n] = __builtin_amdgcn_mfma_f32_16x16x32_bf16(al[m], bh[n], acc[m][n], 0, 0, 0);
        }
    }
    if (!more) break;
    __syncthreads();
    split_write();
    __syncthreads();
    k0 = kn;
  }
  float* Ap = Acc + (size_t)bz * 640 * DF;
#pragma unroll
  for (int m = 0; m < 4; ++m)
#pragma unroll
    for (int n = 0; n < 4; ++n)
#pragma unroll
      for (int r = 0; r < 4; ++r) {
        int row = by * 128 + wr * 64 + m * 16 + quad * 4 + r;
        int col = colBase + wc * 64 + n * 16 + l16;
        Ap[(size_t)row * DF + col] = acc[m][n][r];
      }
  // ---- finisher election: 8th arrival for this tile reduces it ----
  __syncthreads();                       // drain C-writes (vmcnt0 before barrier)
  if (tid == 0) {
    sOld = __hip_atomic_fetch_add(&tcnt[by * 5 + bx], 1u,
                                  __ATOMIC_ACQ_REL, __HIP_MEMORY_SCOPE_AGENT);
  }
  __syncthreads();
  if (((sOld + 1u) & 7u) != 0u) return;  // exactly one finisher per tile
  // finisher: sum 8 slices (same order as old feat_reduce) -> Kh/Kl/FX
  for (int e = tid; e < 128 * 128; e += 256) {
    int rr = e >> 7, cc = e & 127;
    int row = by * 128 + rr, col = colBase + cc;
    size_t idx = (size_t)row * DF + col;
    float v = 0.f;
#pragma unroll
    for (int s = 0; s < KSPLIT; ++s) v += Acc[idx + (size_t)s * 409600];
    if (row < MROWS) {
      short h, l; split_sh(v, h, l);
      Kh[idx] = h;
      Kl[idx] = l;
    } else {
      FX[(size_t)(row - MROWS) * DF + col] = v;
    }
  }
  if (by == 0 && bx == 0) {
    if (tid < 16) zbuf[tid] = 0.f;       // bar + mflag
    for (int e = tid; e < QROWS * NRHS; e += 256) out[e] = 0.f;
  }
}

// ---- MFMA: A(416x416) = K K^T + 50 I (zero-padded), bf16 hi/lo out --------
__global__ __launch_bounds__(256) void gemm_aul(const short* __restrict__ Kh,
                                                const short* __restrict__ Kl,
                                                short* __restrict__ Aph,
                                                short* __restrict__ Apl) {
  int tid = threadIdx.x;
  int wave = tid >> 6, lane = tid & 63;
  int l16 = lane & 15, quad = lane >> 4;
  int row0 = blockIdx.y * 64 + wave * 16;
  int colBase = blockIdx.x * 64;
  bool aValid = (row0 < MROWS);
  const bf8v bzero = {0,0,0,0,0,0,0,0};
  f32x4 acc[4] = {{0,0,0,0},{0,0,0,0},{0,0,0,0},{0,0,0,0}};
  for (int k0 = 0; k0 < DF; k0 += 32) {
    int ka = k0 + quad * 8;
    bf8v ah = bzero, al = bzero;
    if (aValid) {
      size_t ao = (size_t)(row0 + l16) * DF + ka;
      ah = *reinterpret_cast<const bf8v*>(Kh + ao);
      al = *reinterpret_cast<const bf8v*>(Kl + ao);
    }
#pragma unroll
    for (int t = 0; t < 4; ++t) {
      int colt = colBase + t * 16;
      bf8v bh = bzero, bl = bzero;
      if (colt < MROWS) {
        size_t bo = (size_t)(colt + l16) * DF + ka;
        bh = *reinterpret_cast<const bf8v*>(Kh + bo);
        bl = *reinterpret_cast<const bf8v*>(Kl + bo);
      }
      acc[t] = __builtin_amdgcn_mfma_f32_16x16x32_bf16(ah, bh, acc[t], 0, 0, 0);
      acc[t] = __builtin_amdgcn_mfma_f32_16x16x32_bf16(ah, bl, acc[t], 0, 0, 0);
      acc[t] = __builtin_amdgcn_mfma_f32_16x16x32_bf16(al, bh, acc[t], 0, 0, 0);
    }
  }
  if (row0 >= PN) return;
#pragma unroll
  for (int t = 0; t < 4; ++t) {
    int colt = colBase + t * 16;
    if (colt >= PN) continue;
#pragma unroll
    for (int r = 0; r < 4; ++r) {
      int row = row0 + quad * 4 + r;
      int col = colt + l16;
      float v = acc[t][r];
      if (row == col && row < MROWS) v += CREG;
      short h, l; split_sh(v, h, l);
      size_t o = (size_t)row * PN + col;
      Aph[o] = h; Apl[o] = l;
    }
  }
}

// ---- fused (512 threads): blocks 0..12 = solve (8-wave, 28 rounds,
//      local-d0, central counter barrier); 13..40 = M (4-wave body). --------
__global__ __launch_bounds__(512) void solve_and_m(const short* __restrict__ Aph,
                                                   const short* __restrict__ Apl,
                                                   const float* __restrict__ FX,
                                                   const short* __restrict__ Kh,
                                                   const short* __restrict__ Kl,
                                                   const float* __restrict__ gamma,
                                                   unsigned* __restrict__ D0,
                                                   unsigned* __restrict__ D1,
                                                   float* __restrict__ V0,
                                                   float* __restrict__ V1,
                                                   unsigned* __restrict__ bar,
                                                   unsigned* __restrict__ mflag,
                                                   float* __restrict__ M,
                                                   float* __restrict__ out) {
  int tid = threadIdx.x, b = blockIdx.x;
  int wave = tid >> 6, lane = tid & 63, l16 = lane & 15, quad = lane >> 4;
  const bf8v bzero = {0,0,0,0,0,0,0,0};

  if (b >= GBLK) {
    // ================= M role: 4-wave proven body; waves 4-7 idle =========
    if (wave < 4) {
      int mt = b - GBLK;             // 0..27
      int mb = mt / 7, nb = mt - (mt / 7) * 7;
      int q0 = mb * 64 + wave * 16;
      f32x4 acc[4] = {{0,0,0,0},{0,0,0,0},{0,0,0,0},{0,0,0,0}};
      int arow = q0 + l16;
      bool aOk = (arow < QROWS);
      const float* fr = FX + (size_t)(aOk ? arow : 0) * DF;
      for (int k0 = 0; k0 < DF; k0 += 32) {
        int ka = k0 + quad * 8;
        bf8v ah = bzero, al = bzero;
        if (aOk) {
          float4 a0 = *reinterpret_cast<const float4*>(fr + ka);
          float4 a1 = *reinterpret_cast<const float4*>(fr + ka + 4);
          float av[8] = {a0.x, a0.y, a0.z, a0.w, a1.x, a1.y, a1.z, a1.w};
#pragma unroll
          for (int j = 0; j < 8; ++j) { short h, l; split_sh(av[j], h, l); ah[j] = h; al[j] = l; }
        }
#pragma unroll
        for (int t = 0; t < 4; ++t) {
          int n = nb * 64 + t * 16 + l16;
          bf8v bh = bzero, bl = bzero;
          if (n < NMAT) {
            bh = *reinterpret_cast<const bf8v*>(Kh + (size_t)n * DF + ka);
            bl = *reinterpret_cast<const bf8v*>(Kl + (size_t)n * DF + ka);
          }
          acc[t] = __builtin_amdgcn_mfma_f32_16x16x32_bf16(ah, bh, acc[t], 0, 0, 0);
          acc[t] = __builtin_amdgcn_mfma_f32_16x16x32_bf16(ah, bl, acc[t], 0, 0, 0);
          acc[t] = __builtin_amdgcn_mfma_f32_16x16x32_bf16(al, bh, acc[t], 0, 0, 0);
        }
      }
#pragma unroll
      for (int t = 0; t < 4; ++t)
#pragma unroll
        for (int r = 0; r < 4; ++r) {
          int row = q0 + quad * 4 + r;
          int col = nb * 64 + t * 16 + l16;
          if (row < QROWS && col < NMAT)
            __hip_atomic_store(&M[(size_t)row * NMAT + col], acc[t][r],
                               __ATOMIC_RELAXED, __HIP_MEMORY_SCOPE_AGENT);
        }
    }
    __syncthreads();
    if (tid == 0)
      __hip_atomic_fetch_add(mflag, 1u, __ATOMIC_RELEASE, __HIP_MEMORY_SCOPE_AGENT);
    return;
  }

  // ================= solve role: 8 waves, own 32 rows of A ================
  __shared__ __align__(16) short Abig[2][SCOLS][DPAD];  // A rows hi/lo, 54.3KB
  __shared__ __align__(16) short dbT[2][NRHS][DPAD];    // d^T hi/lo,   27.1KB
  __shared__ float yred[8][SCOLS][17];                  // per-wave partials, 17.4KB
  __shared__ float vprevL[PN], vcurL[PN];               // full PV vectors
  __shared__ float XsL[SCOLS][NRHS + 1];                // own X slice
  __shared__ float scal[2];
  __shared__ float rn[8], rd[8];
  int r0 = b * SCOLS;

  // load own 32 rows of A (hi+lo), contiguous
  for (int e = tid; e < SCOLS * 52; e += 512) {
    int i = e / 52, c = e - i * 52;
    *reinterpret_cast<bf8v*>(&Abig[0][i][c * 8]) =
        *reinterpret_cast<const bf8v*>(Aph + (size_t)(r0 + i) * PN + c * 8);
    *reinterpret_cast<bf8v*>(&Abig[1][i][c * 8]) =
        *reinterpret_cast<const bf8v*>(Apl + (size_t)(r0 + i) * PN + c * 8);
  }
  // zero d^T; init v0
  for (int e = tid; e < NRHS * DPAD; e += 512) {
    (&dbT[0][0][0])[e] = 0; (&dbT[1][0][0])[e] = 0;
  }
  if (tid < PN) {
    float v = (tid < NMAT) ? (1.f + 0.125f * (float)(tid & 7)) : 0.f;
    vcurL[tid] = v;
    dbT[0][0][tid] = bf16_rn(v);
  }
  __syncthreads();

  unsigned ph = 0;
  auto gridbar = [&]() {
    __syncthreads();
    ++ph;
    if (tid == 0) {
      unsigned tgt = ph * GBLK;
      __hip_atomic_fetch_add(bar, 1u, __ATOMIC_RELEASE, __HIP_MEMORY_SCOPE_AGENT);
      while (__hip_atomic_load(bar, __ATOMIC_RELAXED, __HIP_MEMORY_SCOPE_AGENT) < tgt)
        __builtin_amdgcn_s_sleep(2);
    }
    __syncthreads();
  };

  // local matvec: y[32x16] = A[own rows][:] @ d; 13 K-tiles over 8 waves
  auto matvec = [&](bool lo) {
    f32x4 acc0 = {0, 0, 0, 0}, acc1 = {0, 0, 0, 0};
    for (int kt = wave; kt < 13; kt += 8) {
      int ko = kt * 32 + quad * 8;
      bf8v bh = *reinterpret_cast<const bf8v*>(&dbT[0][l16][ko]);
      bf8v ah0 = *reinterpret_cast<const bf8v*>(&Abig[0][l16][ko]);
      bf8v ah1 = *reinterpret_cast<const bf8v*>(&Abig[0][16 + l16][ko]);
      acc0 = __builtin_amdgcn_mfma_f32_16x16x32_bf16(ah0, bh, acc0, 0, 0, 0);
      acc1 = __builtin_amdgcn_mfma_f32_16x16x32_bf16(ah1, bh, acc1, 0, 0, 0);
      if (lo) {
        bf8v bl = *reinterpret_cast<const bf8v*>(&dbT[1][l16][ko]);
        bf8v al0 = *reinterpret_cast<const bf8v*>(&Abig[1][l16][ko]);
        bf8v al1 = *reinterpret_cast<const bf8v*>(&Abig[1][16 + l16][ko]);
        acc0 = __builtin_amdgcn_mfma_f32_16x16x32_bf16(ah0, bl, acc0, 0, 0, 0);
        acc0 = __builtin_amdgcn_mfma_f32_16x16x32_bf16(al0, bh, acc0, 0, 0, 0);
        acc1 = __builtin_amdgcn_mfma_f32_16x16x32_bf16(ah1, bl, acc1, 0, 0, 0);
        acc1 = __builtin_amdgcn_mfma_f32_16x16x32_bf16(al1, bh, acc1, 0, 0, 0);
      }
    }
#pragma unroll
    for (int r_ = 0; r_ < 4; ++r_) {
      yred[wave][quad * 4 + r_][l16] = acc0[r_];
      yred[wave][16 + quad * 4 + r_][l16] = acc1[r_];
    }
  };

  // ---- power iteration: local y slice, broadcast full v ----
  for (int s = 0; s < PVSTEPS; ++s) {
    matvec(false);
    __syncthreads();
    if (tid < SCOLS) {
      float y = 0.f;
#pragma unroll
      for (int w = 0; w < 8; ++w) y += yred[w][tid][0];
      float* Vb = (s & 1) ? V1 : V0;
      __hip_atomic_store(&Vb[r0 + tid], y, __ATOMIC_RELAXED, __HIP_MEMORY_SCOPE_AGENT);
    }
    gridbar();
    const float* Vb = (s & 1) ? V1 : V0;
    if (s == PVSTEPS - 1 && tid < PN) vprevL[tid] = vcurL[tid];
    if (tid < PN) {
      float g0 = __hip_atomic_load((float*)&Vb[tid], __ATOMIC_RELAXED, __HIP_MEMORY_SCOPE_AGENT);
      float v = g0 * (1.f / 4096.f);
      vcurL[tid] = v;
      dbT[0][0][tid] = bf16_rn(v);
    }
    __syncthreads();
  }

  // ---- Rayleigh quotient: computed locally in every block ----
  {
    float n = 0.f, dd = 0.f;
    if (tid < PN) {
      n = vprevL[tid] * vcurL[tid];
      dd = vprevL[tid] * vprevL[tid];
    }
#pragma unroll
    for (int o = 32; o; o >>= 1) {
      n += __shfl_down(n, o);
      dd += __shfl_down(dd, o);
    }
    if (lane == 0) { rn[wave] = n; rd[wave] = dd; }
    __syncthreads();
    if (tid == 0) {
      float N = 0.f, D = 0.f;
#pragma unroll
      for (int w = 0; w < 8; ++w) { N += rn[w]; D += rd[w]; }
      float rqv = 4096.f * N / D;
      float bb = 1.3f * rqv;
      if (!(bb > 800.f)) bb = 12000.f;   // degenerate/NaN fallback
      if (bb > 100000.f) bb = 100000.f;
      scal[0] = 0.5f * (bb + CREG);      // theta
      scal[1] = 0.5f * (bb - CREG);      // delta
    }
    __syncthreads();
  }
  float theta = scal[0], delta = scal[1];
  float sigma = theta / delta, rho = 1.f / sigma;

  // ---- Chebyshev init: d0 local (no exchange); 1 (row,c) pair per thread --
  float xr, rr, dr;
  {
    int rl = tid >> 4, c = tid & 15, gi = r0 + rl;   // 512 threads = 32x16
    float pc = (gi < NMAT && (gi / 25) == c) ? 1.f : 0.f;
    xr = 0.f; rr = pc; dr = pc / theta;
  }
  for (int e = tid; e < PN * NRHS; e += 512) {
    int row = e >> 4, c = e & 15;
    float pc = (row < NMAT && (row / 25) == c) ? 1.f : 0.f;
    float d0v = pc / theta;
    short h, l; split_sh(d0v, h, l);
    dbT[0][c][row] = h; dbT[1][c][row] = l;
  }
  __syncthreads();

  // ---- Chebyshev steps (Saad Alg 12.1); CSTEPS-1 matvecs + final add ----
  for (int k = 0; k < CSTEPS - 1; ++k) {
    matvec(true);
    __syncthreads();
    float rho1 = 1.f / (2.f * sigma - rho);
    float s1 = rho1 * rho, s2 = 2.f * rho1 / delta;
    rho = rho1;
    unsigned* Db = (k & 1) ? D0 : D1;              // buffer for d_{k+1}
    {
      int rl = tid >> 4, c = tid & 15, gi = r0 + rl;
      float mv = 0.f;
#pragma unroll
      for (int w = 0; w < 8; ++w) mv += yred[w][rl][c];
      xr += dr;
      rr -= mv;
      float dn = s1 * dr + s2 * rr;
      dr = dn;
      if (k < CSTEPS - 2) {
        short h, l; split_sh(dn, h, l);
        __hip_atomic_store(&Db[(size_t)gi * NRHS + c],
                           ((unsigned)(unsigned short)h << 16) | (unsigned)(unsigned short)l,
                           __ATOMIC_RELAXED, __HIP_MEMORY_SCOPE_AGENT);
      }
    }
    if (k < CSTEPS - 2) {
      gridbar();
      unsigned gw[13];
#pragma unroll
      for (int j = 0; j < 13; ++j)
        gw[j] = __hip_atomic_load(&Db[tid + 512 * j], __ATOMIC_RELAXED, __HIP_MEMORY_SCOPE_AGENT);
#pragma unroll
      for (int j = 0; j < 13; ++j) {
        int e = tid + 512 * j, row = e >> 4, c = e & 15;
        dbT[0][c][row] = (short)(gw[j] >> 16);
        dbT[1][c][row] = (short)gw[j];
      }
    }
    __syncthreads();
  }

  // ---- fused logits epilogue: out[q][c] += -gamma * M[q, own] . X[own, c] --
  {
    int rl = tid >> 4, c = tid & 15;
    XsL[rl][c] = xr + dr;
  }
  __syncthreads();
  if (tid == 0) {
    while (__hip_atomic_load(mflag, __ATOMIC_RELAXED, __HIP_MEMORY_SCOPE_AGENT) < MTILES)
      __builtin_amdgcn_s_sleep(2);
  }
  __syncthreads();
  float* Msl = reinterpret_cast<float*>(&Abig[0][0][0]);  // 240*32*4 = 30.7KB <= 54.3KB
  {
    float gm[15];
#pragma unroll
    for (int j = 0; j < 15; ++j) {
      int e = tid + 512 * j;      // < 7680 = 240*32
      int q = e >> 5, i = e & 31;
      gm[j] = (r0 + i < NMAT)
                  ? __hip_atomic_load(&M[(size_t)q * NMAT + r0 + i],
                                      __ATOMIC_RELAXED, __HIP_MEMORY_SCOPE_AGENT)
                  : 0.f;
    }
#pragma unroll
    for (int j = 0; j < 15; ++j) Msl[tid + 512 * j] = gm[j];
  }
  __syncthreads();
  float g = -gamma[0];
  int c = tid & 15;
  for (int q = tid >> 4; q < QROWS; q += 32) {
    float s = 0.f;
#pragma unroll
    for (int i = 0; i < SCOLS; ++i) s += Msl[q * SCOLS + i] * XsL[i][c];
    atomicAdd(&out[q * NRHS + c], g * s);
  }
}

extern "C" void kernel_launch(void* const* d_in, const int* in_sizes, int n_in,
                              void* d_out, int out_size, void* d_ws, size_t ws_size,
                              hipStream_t stream) {
  const float* S = (const float*)d_in[0];
  const float* Qm = (const float*)d_in[1];
  const float* Wb = (const float*)d_in[2];
  const float* gamma = (const float*)d_in[3];
  float* out = (float*)d_out;
  char* base = (char*)d_ws;
  short* Kh   = (short*)(base);                  // 400*640*2 = 512,000
  short* Kl   = (short*)(base + 512000);         // 512,000
  float* FX   = (float*)(base + 1024000);        // 240*640*4 = 614,400
  short* Aph  = (short*)(base + 1638400);        // 416*416*2 = 346,112
  short* Apl  = (short*)(base + 1984512);        // 346,112
  float* Mm   = (float*)(base + 2330624);        // 240*400*4 = 384,000
  unsigned* bar = (unsigned*)(base + 2740224);   // ctrl (64 B): bar, mflag
  unsigned* mflag = (unsigned*)(base + 2740240);
  float* zbuf = (float*)(base + 2740224);        // zero region: ctrl (16 f)
  unsigned* D0 = (unsigned*)(base + 2740288);    // 416*16*4 = 26,624 (d ping)
  unsigned* D1 = (unsigned*)(base + 2766912);    // 26,624 (d pong)
  float* V0   = (float*)(base + 2793536);        // 416*4 = 1,664 (PV ping)
  float* V1   = (float*)(base + 2795200);        // 1,664 -> end 2,796,864
  float* Acc  = (float*)(base + 2796864);        // 8*640*640*4 = 13,107,200
  unsigned* tcnt = (unsigned*)(base + 15904064); // 25 tile counters (mod-8,
                                                 // init-agnostic; no reset)
                                                 // -> total 15,904,192 B

  gemm_feat_sk<<<dim3(5, 5, KSPLIT), 256, 0, stream>>>(S, Qm, Wb, Acc, tcnt,
                                                       Kh, Kl, FX, zbuf, out);
  gemm_aul<<<dim3(7, 7), 256, 0, stream>>>(Kh, Kl, Aph, Apl);
  solve_and_m<<<GBLK + MTILES, 512, 0, stream>>>(Aph, Apl, FX, Kh, Kl, gamma,
                                                 D0, D1, V0, V1, bar, mflag,
                                                 Mm, out);
}

// Round 19
// 202.210 us; speedup vs baseline: 1.1645x; 1.1645x over previous
//
#include <hip/hip_runtime.h>
#include <math.h>

#define DIN 3072
#define DF 640
#define MROWS 400
#define QROWS 240
#define NMAT 400
#define PN 416          // padded A dim (13*32, 26*16)
#define NRHS 16
#define CREG 50.0f
#define PVSTEPS 5
#define CSTEPS 25       // Chebyshev: 2*q^25 ~ 3.5e-3 rel (q~0.78)
#define KSPLIT 8        // feat split-K factor
#define GBLK 13         // solve blocks; each owns 32 ROWS of A in LDS
#define SCOLS 32        // rows per solve block
#define FPAD 72         // feat staging pad (2-way-free banks, r8-proven)
#define MTILES 28       // M = FX@K^T: 4 row-tiles x 7 col-tiles of 64
#define DPAD 424        // 416+8 shorts

typedef __attribute__((ext_vector_type(8))) short bf8v;   // 8 bf16 (4 VGPRs)
typedef __attribute__((ext_vector_type(4))) short s4v;    // 4 bf16 (8 B)
typedef __attribute__((ext_vector_type(4))) float f32x4;  // MFMA acc

__device__ __forceinline__ short bf16_rn(float x) {
  unsigned u = __float_as_uint(x);
  u += 0x7FFFu + ((u >> 16) & 1u);
  return (short)(u >> 16);
}
__device__ __forceinline__ void split_sh(float x, short& h, short& l) {
  h = bf16_rn(x);
  float hf = __uint_as_float(((unsigned)(unsigned short)h) << 16);
  l = bf16_rn(x - hf);
}

// ---- feat split-K=8, 128x128 tiles (r11-proven, best measured) ------------
__global__ __launch_bounds__(256) void gemm_feat_sk(const float* __restrict__ S,
                                                    const float* __restrict__ Qm,
                                                    const float* __restrict__ Wb,
                                                    float* __restrict__ Acc) {
  __shared__ short Ash[128][FPAD];   // 18.4KB each; total 72KB
  __shared__ short Asl[128][FPAD];
  __shared__ short Bsh[128][FPAD];   // [col][k]
  __shared__ short Bsl[128][FPAD];
  int tid = threadIdx.x;
  int wave = tid >> 6, lane = tid & 63, l16 = lane & 15, quad = lane >> 4;
  int wr = wave >> 1, wc = wave & 1;
  int by = blockIdx.y, bx = blockIdx.x, bz = blockIdx.z;
  int colBase = bx * 128;
  int kbeg = bz * (DIN / KSPLIT), kend = kbeg + (DIN / KSPLIT);
  int kc4 = (tid & 15) * 4;
  float4 ar4[8], br4[8];
  auto load_regs = [&](int kk) {
#pragma unroll
    for (int p = 0; p < 8; ++p) {
      int ar_ = by * 128 + (tid >> 4) + 16 * p;
      const float* srp = (ar_ < MROWS) ? (S + (size_t)ar_ * DIN)
                                       : (Qm + (size_t)(ar_ - MROWS) * DIN);
      ar4[p] = *reinterpret_cast<const float4*>(srp + kk + kc4);
      int kr = (tid >> 4) + 16 * (p & 3);
      int cb = colBase + (p >> 2) * 64 + kc4;
      br4[p] = *reinterpret_cast<const float4*>(Wb + (size_t)(kk + kr) * DF + cb);
    }
  };
  auto split_write = [&]() {
#pragma unroll
    for (int p = 0; p < 8; ++p) {
      int row = (tid >> 4) + 16 * p;
      s4v hv, lv; short h, l;
      split_sh(ar4[p].x, h, l); hv[0] = h; lv[0] = l;
      split_sh(ar4[p].y, h, l); hv[1] = h; lv[1] = l;
      split_sh(ar4[p].z, h, l); hv[2] = h; lv[2] = l;
      split_sh(ar4[p].w, h, l); hv[3] = h; lv[3] = l;
      *reinterpret_cast<s4v*>(&Ash[row][kc4]) = hv;
      *reinterpret_cast<s4v*>(&Asl[row][kc4]) = lv;
      int kr = (tid >> 4) + 16 * (p & 3);
      int cb = (p >> 2) * 64 + kc4;          // local col
      split_sh(br4[p].x, h, l); Bsh[cb + 0][kr] = h; Bsl[cb + 0][kr] = l;
      split_sh(br4[p].y, h, l); Bsh[cb + 1][kr] = h; Bsl[cb + 1][kr] = l;
      split_sh(br4[p].z, h, l); Bsh[cb + 2][kr] = h; Bsl[cb + 2][kr] = l;
      split_sh(br4[p].w, h, l); Bsh[cb + 3][kr] = h; Bsl[cb + 3][kr] = l;
    }
  };
  f32x4 acc[4][4];
#pragma unroll
  for (int m = 0; m < 4; ++m)
#pragma unroll
    for (int n = 0; n < 4; ++n) acc[m][n] = {0, 0, 0, 0};
  load_regs(kbeg);
  split_write();
  __syncthreads();
  int k0 = kbeg;
  while (true) {
    int kn = k0 + 64;
    bool more = (kn < kend);
    if (more) load_regs(kn);            // prefetch overlaps MFMA below
#pragma unroll
    for (int kk = 0; kk < 64; kk += 32) {
      int ko = kk + quad * 8;
      bf8v ah[4], al[4], bh[4], bl[4];
#pragma unroll
      for (int m = 0; m < 4; ++m) {
        ah[m] = *reinterpret_cast<const bf8v*>(&Ash[wr * 64 + m * 16 + l16][ko]);
        al[m] = *reinterpret_cast<const bf8v*>(&Asl[wr * 64 + m * 16 + l16][ko]);
      }
#pragma unroll
      for (int n = 0; n < 4; ++n) {
        bh[n] = *reinterpret_cast<const bf8v*>(&Bsh[wc * 64 + n * 16 + l16][ko]);
        bl[n] = *reinterpret_cast<const bf8v*>(&Bsl[wc * 64 + n * 16 + l16][ko]);
      }
#pragma unroll
      for (int m = 0; m < 4; ++m)
#pragma unroll
        for (int n = 0; n < 4; ++n) {
          acc[m][n] = __builtin_amdgcn_mfma_f32_16x16x32_bf16(ah[m], bh[n], acc[m][n], 0, 0, 0);
          acc[m][n] = __builtin_amdgcn_mfma_f32_16x16x32_bf16(ah[m], bl[n], acc[m][n], 0, 0, 0);
          acc[m][n] = __builtin_amdgcn_mfma_f32_16x16x32_bf16(al[m], bh[n], acc[m][n], 0, 0, 0);
        }
    }
    if (!more) break;
    __syncthreads();
    split_write();
    __syncthreads();
    k0 = kn;
  }
  float* Ap = Acc + (size_t)bz * 640 * DF;
#pragma unroll
  for (int m = 0; m < 4; ++m)
#pragma unroll
    for (int n = 0; n < 4; ++n)
#pragma unroll
      for (int r = 0; r < 4; ++r) {
        int row = by * 128 + wr * 64 + m * 16 + quad * 4 + r;
        int col = colBase + wc * 64 + n * 16 + l16;
        Ap[(size_t)row * DF + col] = acc[m][n][r];
      }
}

// ---- reduce 8 partial slices -> Kh/Kl / FX; blk0 zeroes ctrl, blk1 out ----
__global__ __launch_bounds__(256) void feat_reduce(const float* __restrict__ Acc,
                                                   short* __restrict__ Kh,
                                                   short* __restrict__ Kl,
                                                   float* __restrict__ FX,
                                                   float* __restrict__ zbuf,
                                                   float* __restrict__ out) {
  int tid = threadIdx.x;
  if (blockIdx.x == 0) {
    if (tid < 16) zbuf[tid] = 0.f;          // bar + mflag
  } else if (blockIdx.x == 1) {
    for (int e = tid; e < QROWS * NRHS; e += 256) out[e] = 0.f;
  }
  int idx = blockIdx.x * 256 + tid;   // < 640*640
  if (idx >= 640 * DF) return;
  float v = 0.f;
#pragma unroll
  for (int s = 0; s < KSPLIT; ++s) v += Acc[idx + (size_t)s * 409600];
  int row = idx / DF, col = idx - row * DF;
  if (row < MROWS) {
    short h, l; split_sh(v, h, l);
    Kh[(size_t)row * DF + col] = h;
    Kl[(size_t)row * DF + col] = l;
  } else {
    FX[(size_t)(row - MROWS) * DF + col] = v;
  }
}

// ---- MFMA: A(416x416) = K K^T + 50 I (zero-padded), bf16 hi/lo out --------
__global__ __launch_bounds__(256) void gemm_aul(const short* __restrict__ Kh,
                                                const short* __restrict__ Kl,
                                                short* __restrict__ Aph,
                                                short* __restrict__ Apl) {
  int tid = threadIdx.x;
  int wave = tid >> 6, lane = tid & 63;
  int l16 = lane & 15, quad = lane >> 4;
  int row0 = blockIdx.y * 64 + wave * 16;
  int colBase = blockIdx.x * 64;
  bool aValid = (row0 < MROWS);
  const bf8v bzero = {0,0,0,0,0,0,0,0};
  f32x4 acc[4] = {{0,0,0,0},{0,0,0,0},{0,0,0,0},{0,0,0,0}};
  for (int k0 = 0; k0 < DF; k0 += 32) {
    int ka = k0 + quad * 8;
    bf8v ah = bzero, al = bzero;
    if (aValid) {
      size_t ao = (size_t)(row0 + l16) * DF + ka;
      ah = *reinterpret_cast<const bf8v*>(Kh + ao);
      al = *reinterpret_cast<const bf8v*>(Kl + ao);
    }
#pragma unroll
    for (int t = 0; t < 4; ++t) {
      int colt = colBase + t * 16;
      bf8v bh = bzero, bl = bzero;
      if (colt < MROWS) {
        size_t bo = (size_t)(colt + l16) * DF + ka;
        bh = *reinterpret_cast<const bf8v*>(Kh + bo);
        bl = *reinterpret_cast<const bf8v*>(Kl + bo);
      }
      acc[t] = __builtin_amdgcn_mfma_f32_16x16x32_bf16(ah, bh, acc[t], 0, 0, 0);
      acc[t] = __builtin_amdgcn_mfma_f32_16x16x32_bf16(ah, bl, acc[t], 0, 0, 0);
      acc[t] = __builtin_amdgcn_mfma_f32_16x16x32_bf16(al, bh, acc[t], 0, 0, 0);
    }
  }
  if (row0 >= PN) return;
#pragma unroll
  for (int t = 0; t < 4; ++t) {
    int colt = colBase + t * 16;
    if (colt >= PN) continue;
#pragma unroll
    for (int r = 0; r < 4; ++r) {
      int row = row0 + quad * 4 + r;
      int col = colt + l16;
      float v = acc[t][r];
      if (row == col && row < MROWS) v += CREG;
      short h, l; split_sh(v, h, l);
      size_t o = (size_t)row * PN + col;
      Aph[o] = h; Apl[o] = l;
    }
  }
}

// ---- fused (512 threads): blocks 0..12 = solve (8-wave, 28 rounds,
//      local-d0); 13..40 = M (4-wave body; waves 4-7 idle). -----------------
__global__ __launch_bounds__(512) void solve_and_m(const short* __restrict__ Aph,
                                                   const short* __restrict__ Apl,
                                                   const float* __restrict__ FX,
                                                   const short* __restrict__ Kh,
                                                   const short* __restrict__ Kl,
                                                   const float* __restrict__ gamma,
                                                   unsigned* __restrict__ D0,
                                                   unsigned* __restrict__ D1,
                                                   float* __restrict__ V0,
                                                   float* __restrict__ V1,
                                                   unsigned* __restrict__ bar,
                                                   unsigned* __restrict__ mflag,
                                                   float* __restrict__ M,
                                                   float* __restrict__ out) {
  int tid = threadIdx.x, b = blockIdx.x;
  int wave = tid >> 6, lane = tid & 63, l16 = lane & 15, quad = lane >> 4;
  const bf8v bzero = {0,0,0,0,0,0,0,0};

  if (b >= GBLK) {
    // ================= M role: 4-wave proven body; waves 4-7 idle =========
    if (wave < 4) {
      int mt = b - GBLK;             // 0..27
      int mb = mt / 7, nb = mt - (mt / 7) * 7;
      int q0 = mb * 64 + wave * 16;
      f32x4 acc[4] = {{0,0,0,0},{0,0,0,0},{0,0,0,0},{0,0,0,0}};
      int arow = q0 + l16;
      bool aOk = (arow < QROWS);
      const float* fr = FX + (size_t)(aOk ? arow : 0) * DF;
      for (int k0 = 0; k0 < DF; k0 += 32) {
        int ka = k0 + quad * 8;
        bf8v ah = bzero, al = bzero;
        if (aOk) {
          float4 a0 = *reinterpret_cast<const float4*>(fr + ka);
          float4 a1 = *reinterpret_cast<const float4*>(fr + ka + 4);
          float av[8] = {a0.x, a0.y, a0.z, a0.w, a1.x, a1.y, a1.z, a1.w};
#pragma unroll
          for (int j = 0; j < 8; ++j) { short h, l; split_sh(av[j], h, l); ah[j] = h; al[j] = l; }
        }
#pragma unroll
        for (int t = 0; t < 4; ++t) {
          int n = nb * 64 + t * 16 + l16;
          bf8v bh = bzero, bl = bzero;
          if (n < NMAT) {
            bh = *reinterpret_cast<const bf8v*>(Kh + (size_t)n * DF + ka);
            bl = *reinterpret_cast<const bf8v*>(Kl + (size_t)n * DF + ka);
          }
          acc[t] = __builtin_amdgcn_mfma_f32_16x16x32_bf16(ah, bh, acc[t], 0, 0, 0);
          acc[t] = __builtin_amdgcn_mfma_f32_16x16x32_bf16(ah, bl, acc[t], 0, 0, 0);
          acc[t] = __builtin_amdgcn_mfma_f32_16x16x32_bf16(al, bh, acc[t], 0, 0, 0);
        }
      }
#pragma unroll
      for (int t = 0; t < 4; ++t)
#pragma unroll
        for (int r = 0; r < 4; ++r) {
          int row = q0 + quad * 4 + r;
          int col = nb * 64 + t * 16 + l16;
          if (row < QROWS && col < NMAT)
            __hip_atomic_store(&M[(size_t)row * NMAT + col], acc[t][r],
                               __ATOMIC_RELAXED, __HIP_MEMORY_SCOPE_AGENT);
        }
    }
    __syncthreads();
    if (tid == 0)
      __hip_atomic_fetch_add(mflag, 1u, __ATOMIC_RELEASE, __HIP_MEMORY_SCOPE_AGENT);
    return;
  }

  // ================= solve role: 8 waves, own 32 rows of A ================
  __shared__ __align__(16) short Abig[2][SCOLS][DPAD];  // A rows hi/lo, 54.3KB
  __shared__ __align__(16) short dbT[2][NRHS][DPAD];    // d^T hi/lo,   27.1KB
  __shared__ float yred[8][SCOLS][17];                  // per-wave partials, 17.4KB
  __shared__ float vprevL[PN], vcurL[PN];               // full PV vectors
  __shared__ float XsL[SCOLS][NRHS + 1];                // own X slice
  __shared__ float scal[2];
  __shared__ float rn[8], rd[8];
  int r0 = b * SCOLS;

  // load own 32 rows of A (hi+lo), contiguous
  for (int e = tid; e < SCOLS * 52; e += 512) {
    int i = e / 52, c = e - i * 52;
    *reinterpret_cast<bf8v*>(&Abig[0][i][c * 8]) =
        *reinterpret_cast<const bf8v*>(Aph + (size_t)(r0 + i) * PN + c * 8);
    *reinterpret_cast<bf8v*>(&Abig[1][i][c * 8]) =
        *reinterpret_cast<const bf8v*>(Apl + (size_t)(r0 + i) * PN + c * 8);
  }
  // zero d^T; init v0
  for (int e = tid; e < NRHS * DPAD; e += 512) {
    (&dbT[0][0][0])[e] = 0; (&dbT[1][0][0])[e] = 0;
  }
  if (tid < PN) {
    float v = (tid < NMAT) ? (1.f + 0.125f * (float)(tid & 7)) : 0.f;
    vcurL[tid] = v;
    dbT[0][0][tid] = bf16_rn(v);
  }
  __syncthreads();

  unsigned ph = 0;
  auto gridbar = [&]() {
    __syncthreads();
    ++ph;
    if (tid == 0) {
      unsigned tgt = ph * GBLK;
      __hip_atomic_fetch_add(bar, 1u, __ATOMIC_RELEASE, __HIP_MEMORY_SCOPE_AGENT);
      while (__hip_atomic_load(bar, __ATOMIC_RELAXED, __HIP_MEMORY_SCOPE_AGENT) < tgt)
        __builtin_amdgcn_s_sleep(2);
    }
    __syncthreads();
  };

  // local matvec: y[32x16] = A[own rows][:] @ d; 13 K-tiles over 8 waves
  auto matvec = [&](bool lo) {
    f32x4 acc0 = {0, 0, 0, 0}, acc1 = {0, 0, 0, 0};
    for (int kt = wave; kt < 13; kt += 8) {
      int ko = kt * 32 + quad * 8;
      bf8v bh = *reinterpret_cast<const bf8v*>(&dbT[0][l16][ko]);
      bf8v ah0 = *reinterpret_cast<const bf8v*>(&Abig[0][l16][ko]);
      bf8v ah1 = *reinterpret_cast<const bf8v*>(&Abig[0][16 + l16][ko]);
      acc0 = __builtin_amdgcn_mfma_f32_16x16x32_bf16(ah0, bh, acc0, 0, 0, 0);
      acc1 = __builtin_amdgcn_mfma_f32_16x16x32_bf16(ah1, bh, acc1, 0, 0, 0);
      if (lo) {
        bf8v bl = *reinterpret_cast<const bf8v*>(&dbT[1][l16][ko]);
        bf8v al0 = *reinterpret_cast<const bf8v*>(&Abig[1][l16][ko]);
        bf8v al1 = *reinterpret_cast<const bf8v*>(&Abig[1][16 + l16][ko]);
        acc0 = __builtin_amdgcn_mfma_f32_16x16x32_bf16(ah0, bl, acc0, 0, 0, 0);
        acc0 = __builtin_amdgcn_mfma_f32_16x16x32_bf16(al0, bh, acc0, 0, 0, 0);
        acc1 = __builtin_amdgcn_mfma_f32_16x16x32_bf16(ah1, bl, acc1, 0, 0, 0);
        acc1 = __builtin_amdgcn_mfma_f32_16x16x32_bf16(al1, bh, acc1, 0, 0, 0);
      }
    }
#pragma unroll
    for (int r_ = 0; r_ < 4; ++r_) {
      yred[wave][quad * 4 + r_][l16] = acc0[r_];
      yred[wave][16 + quad * 4 + r_][l16] = acc1[r_];
    }
  };

  // ---- power iteration: local y slice, broadcast full v ----
  for (int s = 0; s < PVSTEPS; ++s) {
    matvec(false);
    __syncthreads();
    if (tid < SCOLS) {
      float y = 0.f;
#pragma unroll
      for (int w = 0; w < 8; ++w) y += yred[w][tid][0];
      float* Vb = (s & 1) ? V1 : V0;
      __hip_atomic_store(&Vb[r0 + tid], y, __ATOMIC_RELAXED, __HIP_MEMORY_SCOPE_AGENT);
    }
    gridbar();
    const float* Vb = (s & 1) ? V1 : V0;
    if (s == PVSTEPS - 1 && tid < PN) vprevL[tid] = vcurL[tid];
    if (tid < PN) {
      float g0 = __hip_atomic_load((float*)&Vb[tid], __ATOMIC_RELAXED, __HIP_MEMORY_SCOPE_AGENT);
      float v = g0 * (1.f / 4096.f);
      vcurL[tid] = v;
      dbT[0][0][tid] = bf16_rn(v);
    }
    __syncthreads();
  }

  // ---- Rayleigh quotient: computed locally in every block ----
  {
    float n = 0.f, dd = 0.f;
    if (tid < PN) {
      n = vprevL[tid] * vcurL[tid];
      dd = vprevL[tid] * vprevL[tid];
    }
#pragma unroll
    for (int o = 32; o; o >>= 1) {
      n += __shfl_down(n, o);
      dd += __shfl_down(dd, o);
    }
    if (lane == 0) { rn[wave] = n; rd[wave] = dd; }
    __syncthreads();
    if (tid == 0) {
      float N = 0.f, D = 0.f;
#pragma unroll
      for (int w = 0; w < 8; ++w) { N += rn[w]; D += rd[w]; }
      float rqv = 4096.f * N / D;
      float bb = 1.3f * rqv;
      if (!(bb > 800.f)) bb = 12000.f;   // degenerate/NaN fallback
      if (bb > 100000.f) bb = 100000.f;
      scal[0] = 0.5f * (bb + CREG);      // theta
      scal[1] = 0.5f * (bb - CREG);      // delta
    }
    __syncthreads();
  }
  float theta = scal[0], delta = scal[1];
  float sigma = theta / delta, rho = 1.f / sigma;

  // ---- Chebyshev init: d0 local (no exchange); 1 (row,c) pair per thread --
  float xr, rr, dr;
  {
    int rl = tid >> 4, c = tid & 15, gi = r0 + rl;   // 512 threads = 32x16
    float pc = (gi < NMAT && (gi / 25) == c) ? 1.f : 0.f;
    xr = 0.f; rr = pc; dr = pc / theta;
  }
  for (int e = tid; e < PN * NRHS; e += 512) {
    int row = e >> 4, c = e & 15;
    float pc = (row < NMAT && (row / 25) == c) ? 1.f : 0.f;
    float d0v = pc / theta;
    short h, l; split_sh(d0v, h, l);
    dbT[0][c][row] = h; dbT[1][c][row] = l;
  }
  __syncthreads();

  // ---- Chebyshev steps (Saad Alg 12.1); CSTEPS-1 matvecs + final add ----
  for (int k = 0; k < CSTEPS - 1; ++k) {
    matvec(true);
    __syncthreads();
    float rho1 = 1.f / (2.f * sigma - rho);
    float s1 = rho1 * rho, s2 = 2.f * rho1 / delta;
    rho = rho1;
    unsigned* Db = (k & 1) ? D0 : D1;              // buffer for d_{k+1}
    {
      int rl = tid >> 4, c = tid & 15, gi = r0 + rl;
      float mv = 0.f;
#pragma unroll
      for (int w = 0; w < 8; ++w) mv += yred[w][rl][c];
      xr += dr;
      rr -= mv;
      float dn = s1 * dr + s2 * rr;
      dr = dn;
      if (k < CSTEPS - 2) {
        short h, l; split_sh(dn, h, l);
        __hip_atomic_store(&Db[(size_t)gi * NRHS + c],
                           ((unsigned)(unsigned short)h << 16) | (unsigned)(unsigned short)l,
                           __ATOMIC_RELAXED, __HIP_MEMORY_SCOPE_AGENT);
      }
    }
    if (k < CSTEPS - 2) {
      gridbar();
      unsigned gw[13];
#pragma unroll
      for (int j = 0; j < 13; ++j)
        gw[j] = __hip_atomic_load(&Db[tid + 512 * j], __ATOMIC_RELAXED, __HIP_MEMORY_SCOPE_AGENT);
#pragma unroll
      for (int j = 0; j < 13; ++j) {
        int e = tid + 512 * j, row = e >> 4, c = e & 15;
        dbT[0][c][row] = (short)(gw[j] >> 16);
        dbT[1][c][row] = (short)gw[j];
      }
    }
    __syncthreads();
  }

  // ---- fused logits epilogue: out[q][c] += -gamma * M[q, own] . X[own, c] --
  {
    int rl = tid >> 4, c = tid & 15;
    XsL[rl][c] = xr + dr;
  }
  __syncthreads();
  if (tid == 0) {
    while (__hip_atomic_load(mflag, __ATOMIC_RELAXED, __HIP_MEMORY_SCOPE_AGENT) < MTILES)
      __builtin_amdgcn_s_sleep(2);
  }
  __syncthreads();
  float* Msl = reinterpret_cast<float*>(&Abig[0][0][0]);  // 240*32*4 = 30.7KB <= 54.3KB
  {
    float gm[15];
#pragma unroll
    for (int j = 0; j < 15; ++j) {
      int e = tid + 512 * j;      // < 7680 = 240*32
      int q = e >> 5, i = e & 31;
      gm[j] = (r0 + i < NMAT)
                  ? __hip_atomic_load(&M[(size_t)q * NMAT + r0 + i],
                                      __ATOMIC_RELAXED, __HIP_MEMORY_SCOPE_AGENT)
                  : 0.f;
    }
#pragma unroll
    for (int j = 0; j < 15; ++j) Msl[tid + 512 * j] = gm[j];
  }
  __syncthreads();
  float g = -gamma[0];
  int c = tid & 15;
  for (int q = tid >> 4; q < QROWS; q += 32) {
    float s = 0.f;
#pragma unroll
    for (int i = 0; i < SCOLS; ++i) s += Msl[q * SCOLS + i] * XsL[i][c];
    atomicAdd(&out[q * NRHS + c], g * s);
  }
}

extern "C" void kernel_launch(void* const* d_in, const int* in_sizes, int n_in,
                              void* d_out, int out_size, void* d_ws, size_t ws_size,
                              hipStream_t stream) {
  const float* S = (const float*)d_in[0];
  const float* Qm = (const float*)d_in[1];
  const float* Wb = (const float*)d_in[2];
  const float* gamma = (const float*)d_in[3];
  float* out = (float*)d_out;
  char* base = (char*)d_ws;
  short* Kh   = (short*)(base);                  // 400*640*2 = 512,000
  short* Kl   = (short*)(base + 512000);         // 512,000
  float* FX   = (float*)(base + 1024000);        // 240*640*4 = 614,400
  short* Aph  = (short*)(base + 1638400);        // 416*416*2 = 346,112
  short* Apl  = (short*)(base + 1984512);        // 346,112
  float* Mm   = (float*)(base + 2330624);        // 240*400*4 = 384,000
  unsigned* bar = (unsigned*)(base + 2740224);   // ctrl (64 B): bar, mflag
  unsigned* mflag = (unsigned*)(base + 2740240);
  float* zbuf = (float*)(base + 2740224);        // zero region: ctrl (16 f)
  unsigned* D0 = (unsigned*)(base + 2740288);    // 416*16*4 = 26,624 (d ping)
  unsigned* D1 = (unsigned*)(base + 2766912);    // 26,624 (d pong)
  float* V0   = (float*)(base + 2793536);        // 416*4 = 1,664 (PV ping)
  float* V1   = (float*)(base + 2795200);        // 1,664 -> end 2,796,864
  float* Acc  = (float*)(base + 2796864);        // 8*640*640*4 = 13,107,200
                                                 // -> total 15,904,064 B

  gemm_feat_sk<<<dim3(5, 5, KSPLIT), 256, 0, stream>>>(S, Qm, Wb, Acc);
  feat_reduce<<<1600, 256, 0, stream>>>(Acc, Kh, Kl, FX, zbuf, out);
  gemm_aul<<<dim3(7, 7), 256, 0, stream>>>(Kh, Kl, Aph, Apl);
  solve_and_m<<<GBLK + MTILES, 512, 0, stream>>>(Aph, Apl, FX, Kh, Kl, gamma,
                                                 D0, D1, V0, V1, bar, mflag,
                                                 Mm, out);
}